// Round 9
// baseline (5663.713 us; speedup 1.0000x reference)
//
#include <hip/hip_runtime.h>

typedef __attribute__((ext_vector_type(8))) short bf16x8;
typedef __attribute__((ext_vector_type(4))) float f32x4;
typedef __attribute__((ext_vector_type(4))) unsigned short u16x4;
typedef __attribute__((ext_vector_type(8))) unsigned short u16x8;

#define B_ 2048
#define A_ 50
#define H_ 512
#define NACT_ 64
#define F_ 562

#define WS_W1T 0
#define WS_W2T ((size_t)A_ * H_ * H_ * 2)
#define WS_B1 (WS_W2T + (size_t)A_ * NACT_ * H_ * 2)
#define WS_B2 (WS_B1 + (size_t)A_ * H_ * 4)
#define WS_AB (WS_B2 + (size_t)A_ * NACT_ * 4)
#define WS_AB_SZ ((size_t)1600 * 512 * 4 * 4)

static __device__ __forceinline__ unsigned short f2bf(float f) {
  unsigned int u = __builtin_bit_cast(unsigned int, f);
  u += 0x7fffu + ((u >> 16) & 1u);
  return (unsigned short)(u >> 16);
}

static __device__ __forceinline__ void gld_lds16(const unsigned short* src,
                                                 unsigned short* dst) {
  __builtin_amdgcn_global_load_lds(
      (const __attribute__((address_space(1))) unsigned int*)(const void*)src,
      (__attribute__((address_space(3))) unsigned int*)(void*)dst, 16, 0, 0);
}

static __device__ __forceinline__ int clamp_r(int r) {
  return r < 0 ? 0 : (r > A_ - 1 ? A_ - 1 : r);
}

// ---- preps (R4 verbatim) ----
__global__ void prep_w1(const float* __restrict__ w1,
                        const int* __restrict__ routing,
                        unsigned short* __restrict__ w1t) {
  const int bid = blockIdx.x;
  const int a = bid / 64;
  const int tile = bid - a * 64;
  const int tk = tile & 7, tj = tile >> 3;
  const int k0 = tk * 64, j0 = tj * 64;
  const int r = clamp_r(routing[a]);
  __shared__ float tl[64][65];
  const int t = threadIdx.x;
  const int c = t & 63, q = t >> 6;
#pragma unroll
  for (int i = 0; i < 16; ++i) {
    const int kl = q + i * 4;
    tl[kl][c] = w1[((size_t)r * F_ + k0 + kl) * H_ + j0 + c];
  }
  __syncthreads();
#pragma unroll
  for (int it = 0; it < 2; ++it) {
    const int jl = t >> 2, c2 = t & 3;
    const int kc = it * 4 + (c2 ^ (jl & 3));
    u16x8 v;
#pragma unroll
    for (int e = 0; e < 8; ++e) v[e] = f2bf(tl[kc * 8 + e][jl]);
    unsigned short* dst = w1t +
        (((size_t)a * 16 + tk * 2 + it) * H_ + j0 + jl) * 32 + c2 * 8;
    *(u16x8*)dst = v;
  }
}

__global__ void prep_w2(const float* __restrict__ w2,
                        const int* __restrict__ routing,
                        unsigned short* __restrict__ w2t) {
  const int bid = blockIdx.x;
  const int a = bid >> 3;
  const int tk = bid & 7;
  const int k0 = tk * 64;
  const int r = clamp_r(routing[a]);
  __shared__ float tl[64][65];
  const int t = threadIdx.x;
  const int c = t & 63, q = t >> 6;
#pragma unroll
  for (int i = 0; i < 16; ++i) {
    const int kl = q + i * 4;
    tl[kl][c] = w2[((size_t)r * H_ + k0 + kl) * NACT_ + c];
  }
  __syncthreads();
#pragma unroll
  for (int i = 0; i < 16; ++i) {
    const int nl = q + i * 4;
    w2t[((size_t)a * NACT_ + nl) * H_ + k0 + c] = f2bf(tl[c][nl]);
  }
}

__global__ void prep_bias(const float* __restrict__ w1,
                          const float* __restrict__ b1,
                          const float* __restrict__ b2,
                          const int* __restrict__ routing,
                          float* __restrict__ bias1, float* __restrict__ bias2) {
  const int a = blockIdx.x;
  const int t = threadIdx.x;
  const int r = clamp_r(routing[a]);
  bias1[a * H_ + t] = b1[(size_t)r * H_ + t] + w1[((size_t)r * F_ + H_ + a) * H_ + t];
  if (t < NACT_) bias2[a * NACT_ + t] = b2[r * NACT_ + t];
}

// ---- ablation template: V=0 FULL(R4), 1 W1+MFMA, 3 MFMA-only, 5 X-only,
//      6 W1-stream-only. REP = loop repeats (lifts above the 119us fill bar).
template <int V, int REP>
__global__ __launch_bounds__(512, 4) void divtree_ab(
    const float* __restrict__ x, const unsigned short* __restrict__ w1t,
    const unsigned short* __restrict__ w2t, const float* __restrict__ bias1,
    const float* __restrict__ bias2, float* __restrict__ out,
    float* __restrict__ abws) {
  constexpr bool HAS_W1 = (V == 0 || V == 1 || V == 6);
  constexpr bool HAS_X = (V == 0 || V == 5);
  constexpr bool HAS_MM = (V == 0 || V == 1 || V == 3);

  __shared__ union {
    struct {
      unsigned short w1[2][H_ * 32];
      unsigned short xs[2][64 * 32];
    } st;
    unsigned short h[64 * H_];
    float outb[64][66];
  } sm;

  const int bid = blockIdx.x;
  const int swz = (bid & 7) * 200 + (bid >> 3);
  const int a = swz >> 5;
  const int b0 = (swz & 31) * 64;

  const int tid = threadIdx.x;
  const int lane = tid & 63;
  const int w = tid >> 6;
  const int l16 = lane & 15;
  const int lk = lane >> 4;
  const int sxor = lk ^ (l16 & 3);
  const int wj = w * 64;
  const unsigned short* w1ta = w1t + (size_t)a * (H_ * H_);
  const int xrow = tid >> 3;
  const int xq = tid & 7;
  const float* xbase =
      x + ((size_t)(b0 + xrow) * A_ + (size_t)a) * H_ + (size_t)xq * 4;
  const int xs_off = xrow * 32 + ((xq >> 1) ^ (xrow & 3)) * 8 + (xq & 1) * 4;
  const int afr_base = (wj + l16) * 32 + sxor * 8;
  const int bfr_base = l16 * 32 + sxor * 8;

  f32x4 acc[4][4];
#pragma unroll
  for (int i = 0; i < 4; ++i)
#pragma unroll
    for (int j = 0; j < 4; ++j) acc[i][j] = (f32x4){0.f, 0.f, 0.f, 0.f};
  f32x4 xr[3];

#pragma unroll 1
  for (int rep = 0; rep < REP; ++rep) {
    // prologue (R4 order, guarded)
    {
      f32x4 xv0;
      if constexpr (HAS_X) xv0 = *(const f32x4*)xbase;
      if constexpr (HAS_W1) {
#pragma unroll
        for (int i = 0; i < 4; ++i)
          gld_lds16(w1ta + ((size_t)(i * 512 + tid) << 3),
                    sm.st.w1[0] + (size_t)(i * 512 + (w << 6)) * 8);
      }
      if constexpr (HAS_X) {
        xr[1] = *(const f32x4*)(xbase + 32);
        xr[2] = *(const f32x4*)(xbase + 64);
        u16x4 v;
#pragma unroll
        for (int e = 0; e < 4; ++e) v[e] = f2bf(xv0[e]);
        *(u16x4*)(sm.st.xs[0] + xs_off) = v;
      }
    }
#pragma unroll
    for (int t = 0; t < 16; ++t) {
      const int buf = t & 1;
      if constexpr (V == 0) {
        if (t <= 13)
          asm volatile("s_waitcnt vmcnt(1) lgkmcnt(0)" ::: "memory");
        else
          asm volatile("s_waitcnt vmcnt(0) lgkmcnt(0)" ::: "memory");
      } else if constexpr (HAS_W1) {
        asm volatile("s_waitcnt vmcnt(0) lgkmcnt(0)" ::: "memory");
      } else {
        asm volatile("s_waitcnt lgkmcnt(0)" ::: "memory");
      }
      __builtin_amdgcn_sched_barrier(0);
      __builtin_amdgcn_s_barrier();
      __builtin_amdgcn_sched_barrier(0);
      asm volatile("" ::: "memory"); // anti-hoist for LDS reads
      if constexpr (HAS_W1) {
        if (t + 1 < 16) {
          const unsigned short* wsrc = w1ta + (size_t)(t + 1) * (H_ * 32);
          unsigned short* wdst = sm.st.w1[buf ^ 1];
#pragma unroll
          for (int i = 0; i < 4; ++i)
            gld_lds16(wsrc + ((size_t)(i * 512 + tid) << 3),
                      wdst + (size_t)(i * 512 + (w << 6)) * 8);
        }
      }
      if constexpr (HAS_X) {
        if (t + 3 < 16)
          xr[(t + 3) % 3] = *(const f32x4*)(xbase + (size_t)(t + 3) * 32);
      }
      if constexpr (HAS_MM) {
        const unsigned short* w1s = sm.st.w1[buf];
        const unsigned short* xss = sm.st.xs[buf];
        bf16x8 bfr[4];
#pragma unroll
        for (int mf = 0; mf < 4; ++mf)
          bfr[mf] = *(const bf16x8*)(xss + bfr_base + mf * (16 * 32));
        __builtin_amdgcn_s_setprio(1);
#pragma unroll
        for (int jf = 0; jf < 4; ++jf) {
          const bf16x8 afr = *(const bf16x8*)(w1s + afr_base + jf * (16 * 32));
#pragma unroll
          for (int mf = 0; mf < 4; ++mf)
            acc[jf][mf] = __builtin_amdgcn_mfma_f32_16x16x32_bf16(
                afr, bfr[mf], acc[jf][mf], 0, 0, 0);
        }
        __builtin_amdgcn_s_setprio(0);
      }
      if constexpr (HAS_X) {
        if (t + 1 < 16) {
          const f32x4 xv = xr[(t + 1) % 3];
          u16x4 v;
#pragma unroll
          for (int e = 0; e < 4; ++e) v[e] = f2bf(xv[e]);
          *(u16x4*)(sm.st.xs[buf ^ 1] + xs_off) = v;
        }
      }
    }
  }
  __syncthreads();

  if constexpr (V != 0) {
    f32x4 s = (f32x4){0.f, 0.f, 0.f, 0.f};
    if constexpr (HAS_MM) {
#pragma unroll
      for (int i = 0; i < 4; ++i)
#pragma unroll
        for (int j = 0; j < 4; ++j) s += acc[i][j];
    } else if constexpr (V == 6) {
      s = *(const f32x4*)((const float*)sm.st.w1[0] + tid * 4);
    } else {
      s = *(const f32x4*)((const float*)sm.st.xs[0] + (tid & 255) * 4);
    }
    *(f32x4*)(abws + ((size_t)bid * 512 + tid) * 4) = s;
    return;
  } else {
    const float* b1p = bias1 + a * H_;
#pragma unroll
    for (int jf = 0; jf < 4; ++jf) {
      const f32x4 bv = *(const f32x4*)(b1p + wj + jf * 16 + lk * 4);
      const int cbase = (wj >> 3) + jf * 2 + (lk >> 1);
      const int half4 = (lk & 1) * 4;
#pragma unroll
      for (int mf = 0; mf < 4; ++mf) {
        u16x4 hv;
#pragma unroll
        for (int r = 0; r < 4; ++r) {
          float f = acc[jf][mf][r] + bv[r];
          f = f > 0.f ? f : 0.f;
          hv[r] = f2bf(f);
        }
        const int m = mf * 16 + l16;
        const int off = m * H_ + ((cbase ^ (l16 & 7))) * 8 + half4;
        *(u16x4*)(sm.h + off) = hv;
      }
    }
    __syncthreads();
    const int m0 = (w & 1) * 32;
    const int n0 = (w >> 1) * 16;
    const unsigned short* w2p =
        w2t + ((size_t)a * NACT_ + n0 + l16) * H_ + lk * 8;
    f32x4 acc2[2];
    acc2[0] = (f32x4){0.f, 0.f, 0.f, 0.f};
    acc2[1] = (f32x4){0.f, 0.f, 0.f, 0.f};
#pragma unroll
    for (int kf = 0; kf < 16; ++kf) {
      const bf16x8 bf2 = *(const bf16x8*)(w2p + kf * 32);
#pragma unroll
      for (int mf = 0; mf < 2; ++mf) {
        const int row = m0 + mf * 16 + l16;
        const int off = row * H_ + (((kf * 4 + lk) ^ (l16 & 7))) * 8;
        const bf16x8 af2 = *(const bf16x8*)(sm.h + off);
        acc2[mf] = __builtin_amdgcn_mfma_f32_16x16x32_bf16(af2, bf2, acc2[mf],
                                                           0, 0, 0);
      }
    }
    const float b2v = bias2[a * NACT_ + n0 + l16];
    __syncthreads();
#pragma unroll
    for (int mf = 0; mf < 2; ++mf)
#pragma unroll
      for (int r = 0; r < 4; ++r)
        sm.outb[m0 + mf * 16 + lk * 4 + r][n0 + l16] = acc2[mf][r] + b2v;
    __syncthreads();
    {
      const int row = tid >> 3;
      const int q8 = (tid & 7) * 8;
      const f32x4 v0 = *(const f32x4*)(&sm.outb[row][q8]);
      const f32x4 v1 = *(const f32x4*)(&sm.outb[row][q8 + 4]);
      float* op = out + ((size_t)(b0 + row) * A_ + a) * NACT_ + q8;
      *(f32x4*)op = v0;
      *(f32x4*)(op + 4) = v1;
    }
  }
}

// V9: barrier-free K-loop. x staged ONCE (stationary, XOR-swizzled);
// W1 fragments global->VGPR (reg double-buffer, counted vmcnt); no LDS
// writes, no barriers in the loop.
template <int REP>
__global__ __launch_bounds__(512, 4) void divtree_v9(
    const float* __restrict__ x, const unsigned short* __restrict__ w1t,
    float* __restrict__ abws) {
  __shared__ unsigned short xs[64 * 512]; // 64 KiB stationary

  const int bid = blockIdx.x;
  const int swz = (bid & 7) * 200 + (bid >> 3);
  const int a = swz >> 5;
  const int b0 = (swz & 31) * 64;

  const int tid = threadIdx.x;
  const int lane = tid & 63;
  const int w = tid >> 6;
  const int l16 = lane & 15;
  const int lk = lane >> 4;
  const int l7 = l16 & 7;
  const int wj = w * 64;

  const unsigned short* w1ta = w1t + (size_t)a * (H_ * H_);

  // stationary x stage: full contiguous rows (256B/thread)
  {
    const int xm = tid >> 3;
    const int xq = tid & 7;
    const float* xrowp =
        x + ((size_t)(b0 + xm) * A_ + (size_t)a) * H_ + (size_t)xq * 64;
    f32x4 xv[16];
#pragma unroll
    for (int i = 0; i < 16; ++i) xv[i] = *(const f32x4*)(xrowp + i * 4);
#pragma unroll
    for (int j = 0; j < 8; ++j) {
      u16x8 v;
#pragma unroll
      for (int e = 0; e < 4; ++e) {
        v[e] = f2bf(xv[2 * j][e]);
        v[4 + e] = f2bf(xv[2 * j + 1][e]);
      }
      const int c = xq * 8 + j;
      *(u16x8*)(xs + xm * 512 + (c ^ (xm & 7)) * 8) = v;
    }
  }
  __syncthreads(); // the only barrier

  // per-lane W1 fragment addresses: slab t, j = wj + jf*16 + l16,
  // chunk lk at pos lk ^ (j&3)  (R4 w1t layout)
  const unsigned short* wfr_base =
      w1ta + ((size_t)(wj + l16)) * 32 + (size_t)((lk ^ (l16 & 3)) * 8);

  f32x4 acc[4][4];
#pragma unroll
  for (int i = 0; i < 4; ++i)
#pragma unroll
    for (int j = 0; j < 4; ++j) acc[i][j] = (f32x4){0.f, 0.f, 0.f, 0.f};

  bf16x8 wrA[4], wrB[4];

#pragma unroll 1
  for (int rep = 0; rep < REP; ++rep) {
    // issue slab 0 -> A
#pragma unroll
    for (int jf = 0; jf < 4; ++jf)
      wrA[jf] = *(const bf16x8*)(wfr_base + jf * (16 * 32));
#pragma unroll
    for (int t = 0; t < 16; ++t) {
      // issue slab t+1 into the other buffer
      if (t + 1 < 16) {
        const unsigned short* p = wfr_base + (size_t)(t + 1) * (H_ * 32);
        if (t & 1) {
#pragma unroll
          for (int jf = 0; jf < 4; ++jf)
            wrA[jf] = *(const bf16x8*)(p + jf * (16 * 32));
        } else {
#pragma unroll
          for (int jf = 0; jf < 4; ++jf)
            wrB[jf] = *(const bf16x8*)(p + jf * (16 * 32));
        }
        asm volatile("s_waitcnt vmcnt(4)" ::: "memory"); // slab t landed
      } else {
        asm volatile("s_waitcnt vmcnt(0)" ::: "memory");
      }
      __builtin_amdgcn_sched_barrier(0);
      const int post = ((t * 4 + lk) ^ l7) * 8;
      bf16x8 bfr[4];
#pragma unroll
      for (int mf = 0; mf < 4; ++mf)
        bfr[mf] = *(const bf16x8*)(xs + (mf * 16 + l16) * 512 + post);
#pragma unroll
      for (int jf = 0; jf < 4; ++jf) {
        const bf16x8 afr = (t & 1) ? wrB[jf] : wrA[jf];
#pragma unroll
        for (int mf = 0; mf < 4; ++mf)
          acc[jf][mf] = __builtin_amdgcn_mfma_f32_16x16x32_bf16(
              afr, bfr[mf], acc[jf][mf], 0, 0, 0);
      }
    }
  }

  f32x4 s = (f32x4){0.f, 0.f, 0.f, 0.f};
#pragma unroll
  for (int i = 0; i < 4; ++i)
#pragma unroll
    for (int j = 0; j < 4; ++j) s += acc[i][j];
  *(f32x4*)(abws + ((size_t)bid * 512 + tid) * 4) = s;
}

extern "C" void kernel_launch(void* const* d_in, const int* in_sizes, int n_in,
                              void* d_out, int out_size, void* d_ws,
                              size_t ws_size, hipStream_t stream) {
  const float* x = (const float*)d_in[0];
  const float* w1 = (const float*)d_in[1];
  const float* b1 = (const float*)d_in[2];
  const float* w2 = (const float*)d_in[3];
  const float* b2 = (const float*)d_in[4];
  const int* routing = (const int*)d_in[5];
  float* out = (float*)d_out;

  char* ws = (char*)d_ws;
  unsigned short* w1t = (unsigned short*)(ws + WS_W1T);
  unsigned short* w2t = (unsigned short*)(ws + WS_W2T);
  float* bias1 = (float*)(ws + WS_B1);
  float* bias2 = (float*)(ws + WS_B2);

  prep_w1<<<A_ * 64, 256, 0, stream>>>(w1, routing, w1t);
  prep_w2<<<A_ * 8, 256, 0, stream>>>(w2, routing, w2t);
  prep_bias<<<A_, 512, 0, stream>>>(w1, b1, b2, routing, bias1, bias2);

  // FULL first (cold anchor, writes d_out)
  divtree_ab<0, 1><<<A_ * 32, 512, 0, stream>>>(x, w1t, w2t, bias1, bias2,
                                                out, nullptr);

  if (ws_size >= WS_AB + WS_AB_SZ) {
    float* abws = (float*)(ws + WS_AB);
    divtree_v9<16><<<A_ * 32, 512, 0, stream>>>(x, w1t, abws);
    divtree_ab<3, 24><<<A_ * 32, 512, 0, stream>>>(x, w1t, w2t, bias1, bias2,
                                                   out, abws);
    divtree_ab<6, 16><<<A_ * 32, 512, 0, stream>>>(x, w1t, w2t, bias1, bias2,
                                                   out, abws);
    divtree_ab<5, 32><<<A_ * 32, 512, 0, stream>>>(x, w1t, w2t, bias1, bias2,
                                                   out, abws);
    divtree_ab<1, 16><<<A_ * 32, 512, 0, stream>>>(x, w1t, w2t, bias1, bias2,
                                                   out, abws);
  }
}

// Round 11
// 156.699 us; speedup vs baseline: 36.1440x; 36.1440x over previous
//
#include <hip/hip_runtime.h>

typedef __attribute__((ext_vector_type(8))) short bf16x8;
typedef __attribute__((ext_vector_type(4))) float f32x4;
typedef __attribute__((ext_vector_type(4))) unsigned short u16x4;
typedef __attribute__((ext_vector_type(8))) unsigned short u16x8;

#define B_ 2048
#define A_ 50
#define H_ 512
#define NACT_ 64
#define F_ 562
#define BM_ 128
#define BK_ 32
#define NSTEP_ 16

#define WS_W1T 0
#define WS_W2T ((size_t)A_ * H_ * H_ * 2)
#define WS_B1 (WS_W2T + (size_t)A_ * NACT_ * H_ * 2)
#define WS_B2 (WS_B1 + (size_t)A_ * H_ * 4)

static __device__ __forceinline__ unsigned short f2bf(float f) {
  unsigned int u = __builtin_bit_cast(unsigned int, f);
  u += 0x7fffu + ((u >> 16) & 1u);
  return (unsigned short)(u >> 16);
}

static __device__ __forceinline__ void gld_lds16(const unsigned short* src,
                                                 unsigned short* dst) {
  __builtin_amdgcn_global_load_lds(
      (const __attribute__((address_space(1))) unsigned int*)(const void*)src,
      (__attribute__((address_space(3))) unsigned int*)(void*)dst, 16, 0, 0);
}

static __device__ __forceinline__ int clamp_r(int r) {
  return r < 0 ? 0 : (r > A_ - 1 ? A_ - 1 : r);
}

// W1T: [a][slab s=k>>5 (16)][j 512][pos 4][e 8]; pos p holds chunk c=p^(j&3).
// Slab = contiguous 32KB. (R4 layout, verbatim)
__global__ void prep_w1(const float* __restrict__ w1,
                        const int* __restrict__ routing,
                        unsigned short* __restrict__ w1t) {
  const int bid = blockIdx.x;
  const int a = bid / 64;
  const int tile = bid - a * 64;
  const int tk = tile & 7, tj = tile >> 3;
  const int k0 = tk * 64, j0 = tj * 64;
  const int r = clamp_r(routing[a]);
  __shared__ float tl[64][65];
  const int t = threadIdx.x;
  const int c = t & 63, q = t >> 6;
#pragma unroll
  for (int i = 0; i < 16; ++i) {
    const int kl = q + i * 4;
    tl[kl][c] = w1[((size_t)r * F_ + k0 + kl) * H_ + j0 + c];
  }
  __syncthreads();
#pragma unroll
  for (int it = 0; it < 2; ++it) {
    const int jl = t >> 2, c2 = t & 3;
    const int kc = it * 4 + (c2 ^ (jl & 3));
    u16x8 v;
#pragma unroll
    for (int e = 0; e < 8; ++e) v[e] = f2bf(tl[kc * 8 + e][jl]);
    unsigned short* dst = w1t +
        (((size_t)a * 16 + tk * 2 + it) * H_ + j0 + jl) * 32 + c2 * 8;
    *(u16x8*)dst = v;
  }
}

__global__ void prep_w2(const float* __restrict__ w2,
                        const int* __restrict__ routing,
                        unsigned short* __restrict__ w2t) {
  const int bid = blockIdx.x;
  const int a = bid >> 3;
  const int tk = bid & 7;
  const int k0 = tk * 64;
  const int r = clamp_r(routing[a]);
  __shared__ float tl[64][65];
  const int t = threadIdx.x;
  const int c = t & 63, q = t >> 6;
#pragma unroll
  for (int i = 0; i < 16; ++i) {
    const int kl = q + i * 4;
    tl[kl][c] = w2[((size_t)r * H_ + k0 + kl) * NACT_ + c];
  }
  __syncthreads();
#pragma unroll
  for (int i = 0; i < 16; ++i) {
    const int nl = q + i * 4;
    w2t[((size_t)a * NACT_ + nl) * H_ + k0 + c] = f2bf(tl[c][nl]);
  }
}

__global__ void prep_bias(const float* __restrict__ w1,
                          const float* __restrict__ b1,
                          const float* __restrict__ b2,
                          const int* __restrict__ routing,
                          float* __restrict__ bias1, float* __restrict__ bias2) {
  const int a = blockIdx.x;
  const int t = threadIdx.x;
  const int r = clamp_r(routing[a]);
  bias1[a * H_ + t] = b1[(size_t)r * H_ + t] + w1[((size_t)r * F_ + H_ + a) * H_ + t];
  if (t < NACT_) bias2[a * NACT_ + t] = b2[r * NACT_ + t];
}

// Main: BM=128, 1024 threads (16 waves). Counted vmcnt(1) with issue order
// PINNED by sched_barrier(0): [gld_lds x2] -> fence -> [x load] -> fence.
// vmcnt retires in order, so vmcnt(1) <=> both W1 glds landed, x in flight.
__global__ __launch_bounds__(1024, 4) void divtree_v11(
    const float* __restrict__ x, const unsigned short* __restrict__ w1t,
    const unsigned short* __restrict__ w2t, const float* __restrict__ bias1,
    const float* __restrict__ bias2, float* __restrict__ out) {
  __shared__ union {
    struct {
      unsigned short w1[2][H_ * BK_];   // 2 x 32 KiB (pre-swizzled slabs)
      unsigned short xs[2][BM_ * BK_];  // 2 x 8 KiB (swizzled rows)
    } st;                               // 80 KiB
    unsigned short h[BM_ * H_];         // 128 KiB (after K-loop)
  } sm;

  // XCD-bijective swizzle: 800 blocks, cpx = 100
  const int bid = blockIdx.x;
  const int swz = (bid & 7) * 100 + (bid >> 3);
  const int a = swz >> 4;
  const int mblk = swz & 15;
  const int b0 = mblk * BM_;

  const int tid = threadIdx.x;
  const int lane = tid & 63;
  const int w = tid >> 6; // wave 0..15
  const int l16 = lane & 15;
  const int lk = lane >> 4;
  const int sxor = lk ^ (l16 & 3);

  // L1 wave tile: 64(j) x 64(m); wave grid 8(j) x 2(m)
  const int wj = (w & 7) * 64;
  const int wm = (w >> 3) * 64;

  const unsigned short* w1ta = w1t + (size_t)a * (H_ * H_);

  const int xrow = tid >> 3;
  const int xq = tid & 7;
  const float* xbase =
      x + ((size_t)(b0 + xrow) * A_ + (size_t)a) * H_ + (size_t)xq * 4;
  const int xs_off = xrow * BK_ + ((xq >> 1) ^ (xrow & 3)) * 8 + (xq & 1) * 4;

  const int afr_base = (wj + l16) * BK_ + sxor * 8;
  const int bfr_base = (wm + l16) * BK_ + sxor * 8;

  f32x4 acc[4][4];
#pragma unroll
  for (int i = 0; i < 4; ++i)
#pragma unroll
    for (int j = 0; j < 4; ++j) acc[i][j] = (f32x4){0.f, 0.f, 0.f, 0.f};

  f32x4 xr[3]; // x(t) prefetch ring, static indices via full unroll

  // ---- prologue: x(0); slab 0 glds; PIN; x(1), x(2); PIN ----
  {
    const f32x4 xv0 = *(const f32x4*)xbase;
#pragma unroll
    for (int i = 0; i < 2; ++i)
      gld_lds16(w1ta + (size_t)(i * 1024 + tid) * 8,
                sm.st.w1[0] + (size_t)(i * 1024 + (w << 6)) * 8);
    __builtin_amdgcn_sched_barrier(0); // glds issued before x prefetches
    xr[1] = *(const f32x4*)(xbase + 1 * BK_);
    xr[2] = *(const f32x4*)(xbase + 2 * BK_);
    __builtin_amdgcn_sched_barrier(0);
    u16x4 v;
#pragma unroll
    for (int e = 0; e < 4; ++e) v[e] = f2bf(xv0[e]);
    *(u16x4*)(sm.st.xs[0] + xs_off) = v;
  }

  // ---- K-loop: one barrier/step, counted vmcnt, pinned issue order ----
#pragma unroll
  for (int t = 0; t < NSTEP_; ++t) {
    const int buf = t & 1;
    if (t <= NSTEP_ - 3)
      asm volatile("s_waitcnt vmcnt(1) lgkmcnt(0)" ::: "memory");
    else
      asm volatile("s_waitcnt vmcnt(0) lgkmcnt(0)" ::: "memory");
    __builtin_amdgcn_sched_barrier(0);
    __builtin_amdgcn_s_barrier();
    __builtin_amdgcn_sched_barrier(0);
    // stage W1 slab t+1 (drained at top of t+1 via vmcnt(1))
    if (t + 1 < NSTEP_) {
      const unsigned short* wsrc = w1ta + (size_t)(t + 1) * (H_ * BK_);
      unsigned short* wdst = sm.st.w1[buf ^ 1];
#pragma unroll
      for (int i = 0; i < 2; ++i)
        gld_lds16(wsrc + (size_t)(i * 1024 + tid) * 8,
                  wdst + (size_t)(i * 1024 + (w << 6)) * 8);
    }
    __builtin_amdgcn_sched_barrier(0); // PIN: glds strictly before x load
    if (t + 3 < NSTEP_)
      xr[(t + 3) % 3] = *(const f32x4*)(xbase + (size_t)(t + 3) * BK_);
    __builtin_amdgcn_sched_barrier(0); // PIN: x load issued here, not later
    // compute: D[j][m] = W1T(j,k) * x(m,k)^T
    const unsigned short* w1s = sm.st.w1[buf];
    const unsigned short* xss = sm.st.xs[buf];
    bf16x8 bfr[4];
#pragma unroll
    for (int mf = 0; mf < 4; ++mf)
      bfr[mf] = *(const bf16x8*)(xss + bfr_base + mf * (16 * BK_));
    __builtin_amdgcn_s_setprio(1);
#pragma unroll
    for (int jf = 0; jf < 4; ++jf) {
      const bf16x8 afr = *(const bf16x8*)(w1s + afr_base + jf * (16 * BK_));
#pragma unroll
      for (int mf = 0; mf < 4; ++mf)
        acc[jf][mf] = __builtin_amdgcn_mfma_f32_16x16x32_bf16(
            afr, bfr[mf], acc[jf][mf], 0, 0, 0);
    }
    __builtin_amdgcn_s_setprio(0);
    // late cvt + xs write for t+1
    if (t + 1 < NSTEP_) {
      const f32x4 xv = xr[(t + 1) % 3];
      u16x4 v;
#pragma unroll
      for (int e = 0; e < 4; ++e) v[e] = f2bf(xv[e]);
      *(u16x4*)(sm.st.xs[buf ^ 1] + xs_off) = v;
    }
  }
  __syncthreads();

  // ---- h = relu(acc + bias1_eff) -> LDS bf16, XOR-swizzled ----
  const float* b1p = bias1 + a * H_;
#pragma unroll
  for (int jf = 0; jf < 4; ++jf) {
    const f32x4 bv = *(const f32x4*)(b1p + wj + jf * 16 + lk * 4);
    const int cbase = (wj >> 3) + jf * 2 + (lk >> 1);
    const int half4 = (lk & 1) * 4;
#pragma unroll
    for (int mf = 0; mf < 4; ++mf) {
      u16x4 hv;
#pragma unroll
      for (int r = 0; r < 4; ++r) {
        float f = acc[jf][mf][r] + bv[r];
        f = f > 0.f ? f : 0.f;
        hv[r] = f2bf(f);
      }
      const int m = wm + mf * 16 + l16;
      const int off = m * H_ + ((cbase ^ (l16 & 7))) * 8 + half4;
      *(u16x4*)(sm.h + off) = hv;
    }
  }
  __syncthreads();

  // ---- layer 2: wave tile 32(m) x 16(n); 16 waves = 4m x 4n ----
  const int m0 = (w & 3) * 32;
  const int n0 = (w >> 2) * 16;
  const unsigned short* w2p =
      w2t + ((size_t)a * NACT_ + n0 + l16) * H_ + lk * 8;
  f32x4 acc2[2];
  acc2[0] = (f32x4){0.f, 0.f, 0.f, 0.f};
  acc2[1] = (f32x4){0.f, 0.f, 0.f, 0.f};
#pragma unroll
  for (int kf = 0; kf < 16; ++kf) {
    const bf16x8 bf2 = *(const bf16x8*)(w2p + kf * 32);
#pragma unroll
    for (int mf = 0; mf < 2; ++mf) {
      const int row = m0 + mf * 16 + l16;
      const int off = row * H_ + (((kf * 4 + lk) ^ (l16 & 7))) * 8;
      const bf16x8 af2 = *(const bf16x8*)(sm.h + off);
      acc2[mf] = __builtin_amdgcn_mfma_f32_16x16x32_bf16(af2, bf2, acc2[mf],
                                                         0, 0, 0);
    }
  }
  const float b2v = bias2[a * NACT_ + n0 + l16];
  __syncthreads(); // all h reads done before outb overwrite (aliased)
  {
    float(*outb)[66] = (float(*)[66])sm.h;
#pragma unroll
    for (int mf = 0; mf < 2; ++mf)
#pragma unroll
      for (int r = 0; r < 4; ++r)
        outb[m0 + mf * 16 + lk * 4 + r][n0 + l16] = acc2[mf][r] + b2v;
    __syncthreads();
    const int row = tid >> 3;
    const int q8 = (tid & 7) * 8;
    const f32x4 v0 = *(const f32x4*)(&outb[row][q8]);
    const f32x4 v1 = *(const f32x4*)(&outb[row][q8 + 4]);
    float* op = out + ((size_t)(b0 + row) * A_ + a) * NACT_ + q8;
    *(f32x4*)op = v0;
    *(f32x4*)(op + 4) = v1;
  }
}

extern "C" void kernel_launch(void* const* d_in, const int* in_sizes, int n_in,
                              void* d_out, int out_size, void* d_ws,
                              size_t ws_size, hipStream_t stream) {
  const float* x = (const float*)d_in[0];
  const float* w1 = (const float*)d_in[1];
  const float* b1 = (const float*)d_in[2];
  const float* w2 = (const float*)d_in[3];
  const float* b2 = (const float*)d_in[4];
  const int* routing = (const int*)d_in[5];
  float* out = (float*)d_out;

  char* ws = (char*)d_ws;
  unsigned short* w1t = (unsigned short*)(ws + WS_W1T);
  unsigned short* w2t = (unsigned short*)(ws + WS_W2T);
  float* bias1 = (float*)(ws + WS_B1);
  float* bias2 = (float*)(ws + WS_B2);

  prep_w1<<<A_ * 64, 256, 0, stream>>>(w1, routing, w1t);
  prep_w2<<<A_ * 8, 256, 0, stream>>>(w2, routing, w2t);
  prep_bias<<<A_, 512, 0, stream>>>(w1, b1, b2, routing, bias1, bias2);
  divtree_v11<<<A_ * (B_ / BM_), 1024, 0, stream>>>(x, w1t, w2t, bias1, bias2,
                                                    out);
}

// Round 12
// 156.529 us; speedup vs baseline: 36.1831x; 1.0011x over previous
//
#include <hip/hip_runtime.h>

typedef __attribute__((ext_vector_type(8))) short bf16x8;
typedef __attribute__((ext_vector_type(4))) float f32x4;
typedef __attribute__((ext_vector_type(4))) unsigned short u16x4;
typedef __attribute__((ext_vector_type(8))) unsigned short u16x8;

#define B_ 2048
#define A_ 50
#define H_ 512
#define NACT_ 64
#define F_ 562
#define BM_ 128
#define BK_ 32
#define NSTEP_ 16

#define WS_W1T 0
#define WS_W2T ((size_t)A_ * H_ * H_ * 2)
#define WS_B1 (WS_W2T + (size_t)A_ * NACT_ * H_ * 2)
#define WS_B2 (WS_B1 + (size_t)A_ * H_ * 4)

static __device__ __forceinline__ unsigned short f2bf(float f) {
  unsigned int u = __builtin_bit_cast(unsigned int, f);
  u += 0x7fffu + ((u >> 16) & 1u);
  return (unsigned short)(u >> 16);
}

static __device__ __forceinline__ void gld_lds16(const unsigned short* src,
                                                 unsigned short* dst) {
  __builtin_amdgcn_global_load_lds(
      (const __attribute__((address_space(1))) unsigned int*)(const void*)src,
      (__attribute__((address_space(3))) unsigned int*)(void*)dst, 16, 0, 0);
}

static __device__ __forceinline__ int clamp_r(int r) {
  return r < 0 ? 0 : (r > A_ - 1 ? A_ - 1 : r);
}

// W1T: [a][slab s=k>>5 (16)][j 512][pos 4][e 8]; pos p holds chunk c=p^(j&3).
// Slab = contiguous 32KB. (R4 layout, verbatim)
__global__ void prep_w1(const float* __restrict__ w1,
                        const int* __restrict__ routing,
                        unsigned short* __restrict__ w1t) {
  const int bid = blockIdx.x;
  const int a = bid / 64;
  const int tile = bid - a * 64;
  const int tk = tile & 7, tj = tile >> 3;
  const int k0 = tk * 64, j0 = tj * 64;
  const int r = clamp_r(routing[a]);
  __shared__ float tl[64][65];
  const int t = threadIdx.x;
  const int c = t & 63, q = t >> 6;
#pragma unroll
  for (int i = 0; i < 16; ++i) {
    const int kl = q + i * 4;
    tl[kl][c] = w1[((size_t)r * F_ + k0 + kl) * H_ + j0 + c];
  }
  __syncthreads();
#pragma unroll
  for (int it = 0; it < 2; ++it) {
    const int jl = t >> 2, c2 = t & 3;
    const int kc = it * 4 + (c2 ^ (jl & 3));
    u16x8 v;
#pragma unroll
    for (int e = 0; e < 8; ++e) v[e] = f2bf(tl[kc * 8 + e][jl]);
    unsigned short* dst = w1t +
        (((size_t)a * 16 + tk * 2 + it) * H_ + j0 + jl) * 32 + c2 * 8;
    *(u16x8*)dst = v;
  }
}

__global__ void prep_w2(const float* __restrict__ w2,
                        const int* __restrict__ routing,
                        unsigned short* __restrict__ w2t) {
  const int bid = blockIdx.x;
  const int a = bid >> 3;
  const int tk = bid & 7;
  const int k0 = tk * 64;
  const int r = clamp_r(routing[a]);
  __shared__ float tl[64][65];
  const int t = threadIdx.x;
  const int c = t & 63, q = t >> 6;
#pragma unroll
  for (int i = 0; i < 16; ++i) {
    const int kl = q + i * 4;
    tl[kl][c] = w2[((size_t)r * H_ + k0 + kl) * NACT_ + c];
  }
  __syncthreads();
#pragma unroll
  for (int i = 0; i < 16; ++i) {
    const int nl = q + i * 4;
    w2t[((size_t)a * NACT_ + nl) * H_ + k0 + c] = f2bf(tl[c][nl]);
  }
}

__global__ void prep_bias(const float* __restrict__ w1,
                          const float* __restrict__ b1,
                          const float* __restrict__ b2,
                          const int* __restrict__ routing,
                          float* __restrict__ bias1, float* __restrict__ bias2) {
  const int a = blockIdx.x;
  const int t = threadIdx.x;
  const int r = clamp_r(routing[a]);
  bias1[a * H_ + t] = b1[(size_t)r * H_ + t] + w1[((size_t)r * F_ + H_ + a) * H_ + t];
  if (t < NACT_) bias2[a * NACT_ + t] = b2[r * NACT_ + t];
}

// Main: BM=128, 1024 threads (16 waves). Counted vmcnt(1) with issue order
// PINNED by sched_barrier(0): [gld_lds x2] -> fence -> [x load] -> fence.
// vmcnt retires in order, so vmcnt(1) <=> both W1 glds landed, x in flight.
__global__ __launch_bounds__(1024, 4) void divtree_v11(
    const float* __restrict__ x, const unsigned short* __restrict__ w1t,
    const unsigned short* __restrict__ w2t, const float* __restrict__ bias1,
    const float* __restrict__ bias2, float* __restrict__ out) {
  __shared__ union {
    struct {
      unsigned short w1[2][H_ * BK_];   // 2 x 32 KiB (pre-swizzled slabs)
      unsigned short xs[2][BM_ * BK_];  // 2 x 8 KiB (swizzled rows)
    } st;                               // 80 KiB
    unsigned short h[BM_ * H_];         // 128 KiB (after K-loop)
  } sm;

  // XCD-bijective swizzle: 800 blocks, cpx = 100
  const int bid = blockIdx.x;
  const int swz = (bid & 7) * 100 + (bid >> 3);
  const int a = swz >> 4;
  const int mblk = swz & 15;
  const int b0 = mblk * BM_;

  const int tid = threadIdx.x;
  const int lane = tid & 63;
  const int w = tid >> 6; // wave 0..15
  const int l16 = lane & 15;
  const int lk = lane >> 4;
  const int sxor = lk ^ (l16 & 3);

  // L1 wave tile: 64(j) x 64(m); wave grid 8(j) x 2(m)
  const int wj = (w & 7) * 64;
  const int wm = (w >> 3) * 64;

  const unsigned short* w1ta = w1t + (size_t)a * (H_ * H_);

  const int xrow = tid >> 3;
  const int xq = tid & 7;
  const float* xbase =
      x + ((size_t)(b0 + xrow) * A_ + (size_t)a) * H_ + (size_t)xq * 4;
  const int xs_off = xrow * BK_ + ((xq >> 1) ^ (xrow & 3)) * 8 + (xq & 1) * 4;

  const int afr_base = (wj + l16) * BK_ + sxor * 8;
  const int bfr_base = (wm + l16) * BK_ + sxor * 8;

  f32x4 acc[4][4];
#pragma unroll
  for (int i = 0; i < 4; ++i)
#pragma unroll
    for (int j = 0; j < 4; ++j) acc[i][j] = (f32x4){0.f, 0.f, 0.f, 0.f};

  f32x4 xr[3]; // x(t) prefetch ring, static indices via full unroll

  // ---- prologue: x(0); slab 0 glds; PIN; x(1), x(2); PIN ----
  {
    const f32x4 xv0 = *(const f32x4*)xbase;
#pragma unroll
    for (int i = 0; i < 2; ++i)
      gld_lds16(w1ta + (size_t)(i * 1024 + tid) * 8,
                sm.st.w1[0] + (size_t)(i * 1024 + (w << 6)) * 8);
    __builtin_amdgcn_sched_barrier(0); // glds issued before x prefetches
    xr[1] = *(const f32x4*)(xbase + 1 * BK_);
    xr[2] = *(const f32x4*)(xbase + 2 * BK_);
    __builtin_amdgcn_sched_barrier(0);
    u16x4 v;
#pragma unroll
    for (int e = 0; e < 4; ++e) v[e] = f2bf(xv0[e]);
    *(u16x4*)(sm.st.xs[0] + xs_off) = v;
  }

  // ---- K-loop: one barrier/step, counted vmcnt, pinned issue order ----
#pragma unroll
  for (int t = 0; t < NSTEP_; ++t) {
    const int buf = t & 1;
    if (t <= NSTEP_ - 3)
      asm volatile("s_waitcnt vmcnt(1) lgkmcnt(0)" ::: "memory");
    else
      asm volatile("s_waitcnt vmcnt(0) lgkmcnt(0)" ::: "memory");
    __builtin_amdgcn_sched_barrier(0);
    __builtin_amdgcn_s_barrier();
    __builtin_amdgcn_sched_barrier(0);
    // stage W1 slab t+1 (drained at top of t+1 via vmcnt(1))
    if (t + 1 < NSTEP_) {
      const unsigned short* wsrc = w1ta + (size_t)(t + 1) * (H_ * BK_);
      unsigned short* wdst = sm.st.w1[buf ^ 1];
#pragma unroll
      for (int i = 0; i < 2; ++i)
        gld_lds16(wsrc + (size_t)(i * 1024 + tid) * 8,
                  wdst + (size_t)(i * 1024 + (w << 6)) * 8);
    }
    __builtin_amdgcn_sched_barrier(0); // PIN: glds strictly before x load
    if (t + 3 < NSTEP_)
      xr[(t + 3) % 3] = *(const f32x4*)(xbase + (size_t)(t + 3) * BK_);
    __builtin_amdgcn_sched_barrier(0); // PIN: x load issued here, not later
    // compute: D[j][m] = W1T(j,k) * x(m,k)^T
    const unsigned short* w1s = sm.st.w1[buf];
    const unsigned short* xss = sm.st.xs[buf];
    bf16x8 bfr[4];
#pragma unroll
    for (int mf = 0; mf < 4; ++mf)
      bfr[mf] = *(const bf16x8*)(xss + bfr_base + mf * (16 * BK_));
    __builtin_amdgcn_s_setprio(1);
#pragma unroll
    for (int jf = 0; jf < 4; ++jf) {
      const bf16x8 afr = *(const bf16x8*)(w1s + afr_base + jf * (16 * BK_));
#pragma unroll
      for (int mf = 0; mf < 4; ++mf)
        acc[jf][mf] = __builtin_amdgcn_mfma_f32_16x16x32_bf16(
            afr, bfr[mf], acc[jf][mf], 0, 0, 0);
    }
    __builtin_amdgcn_s_setprio(0);
    // late cvt + xs write for t+1
    if (t + 1 < NSTEP_) {
      const f32x4 xv = xr[(t + 1) % 3];
      u16x4 v;
#pragma unroll
      for (int e = 0; e < 4; ++e) v[e] = f2bf(xv[e]);
      *(u16x4*)(sm.st.xs[buf ^ 1] + xs_off) = v;
    }
  }
  __syncthreads();

  // ---- h = relu(acc + bias1_eff) -> LDS bf16, XOR-swizzled ----
  const float* b1p = bias1 + a * H_;
#pragma unroll
  for (int jf = 0; jf < 4; ++jf) {
    const f32x4 bv = *(const f32x4*)(b1p + wj + jf * 16 + lk * 4);
    const int cbase = (wj >> 3) + jf * 2 + (lk >> 1);
    const int half4 = (lk & 1) * 4;
#pragma unroll
    for (int mf = 0; mf < 4; ++mf) {
      u16x4 hv;
#pragma unroll
      for (int r = 0; r < 4; ++r) {
        float f = acc[jf][mf][r] + bv[r];
        f = f > 0.f ? f : 0.f;
        hv[r] = f2bf(f);
      }
      const int m = wm + mf * 16 + l16;
      const int off = m * H_ + ((cbase ^ (l16 & 7))) * 8 + half4;
      *(u16x4*)(sm.h + off) = hv;
    }
  }
  __syncthreads();

  // ---- layer 2: wave tile 32(m) x 16(n); 16 waves = 4m x 4n ----
  const int m0 = (w & 3) * 32;
  const int n0 = (w >> 2) * 16;
  const unsigned short* w2p =
      w2t + ((size_t)a * NACT_ + n0 + l16) * H_ + lk * 8;
  f32x4 acc2[2];
  acc2[0] = (f32x4){0.f, 0.f, 0.f, 0.f};
  acc2[1] = (f32x4){0.f, 0.f, 0.f, 0.f};
#pragma unroll
  for (int kf = 0; kf < 16; ++kf) {
    const bf16x8 bf2 = *(const bf16x8*)(w2p + kf * 32);
#pragma unroll
    for (int mf = 0; mf < 2; ++mf) {
      const int row = m0 + mf * 16 + l16;
      const int off = row * H_ + (((kf * 4 + lk) ^ (l16 & 7))) * 8;
      const bf16x8 af2 = *(const bf16x8*)(sm.h + off);
      acc2[mf] = __builtin_amdgcn_mfma_f32_16x16x32_bf16(af2, bf2, acc2[mf],
                                                         0, 0, 0);
    }
  }
  const float b2v = bias2[a * NACT_ + n0 + l16];
  __syncthreads(); // all h reads done before outb overwrite (aliased)
  {
    float(*outb)[66] = (float(*)[66])sm.h;
#pragma unroll
    for (int mf = 0; mf < 2; ++mf)
#pragma unroll
      for (int r = 0; r < 4; ++r)
        outb[m0 + mf * 16 + lk * 4 + r][n0 + l16] = acc2[mf][r] + b2v;
    __syncthreads();
    const int row = tid >> 3;
    const int q8 = (tid & 7) * 8;
    const f32x4 v0 = *(const f32x4*)(&outb[row][q8]);
    const f32x4 v1 = *(const f32x4*)(&outb[row][q8 + 4]);
    float* op = out + ((size_t)(b0 + row) * A_ + a) * NACT_ + q8;
    *(f32x4*)op = v0;
    *(f32x4*)(op + 4) = v1;
  }
}

extern "C" void kernel_launch(void* const* d_in, const int* in_sizes, int n_in,
                              void* d_out, int out_size, void* d_ws,
                              size_t ws_size, hipStream_t stream) {
  const float* x = (const float*)d_in[0];
  const float* w1 = (const float*)d_in[1];
  const float* b1 = (const float*)d_in[2];
  const float* w2 = (const float*)d_in[3];
  const float* b2 = (const float*)d_in[4];
  const int* routing = (const int*)d_in[5];
  float* out = (float*)d_out;

  char* ws = (char*)d_ws;
  unsigned short* w1t = (unsigned short*)(ws + WS_W1T);
  unsigned short* w2t = (unsigned short*)(ws + WS_W2T);
  float* bias1 = (float*)(ws + WS_B1);
  float* bias2 = (float*)(ws + WS_B2);

  prep_w1<<<A_ * 64, 256, 0, stream>>>(w1, routing, w1t);
  prep_w2<<<A_ * 8, 256, 0, stream>>>(w2, routing, w2t);
  prep_bias<<<A_, 512, 0, stream>>>(w1, b1, b2, routing, bias1, bias2);
  divtree_v11<<<A_ * (B_ / BM_), 1024, 0, stream>>>(x, w1t, w2t, bias1, bias2,
                                                    out);
}